// Round 1
// baseline (614.773 us; speedup 1.0000x reference)
//
#include <hip/hip_runtime.h>
#include <stdint.h>

#define B_ 2
#define E_ 8
#define N_ 1024
#define D_ 1024
#define H_ 4096

typedef float f32x4 __attribute__((ext_vector_type(4)));
typedef __bf16 bf16x8 __attribute__((ext_vector_type(8)));

__device__ __forceinline__ unsigned short f2bf(float f) {
  union { float f; uint32_t u; } v; v.f = f;
  uint32_t u = v.u;
  return (unsigned short)((u + 0x7FFFu + ((u >> 16) & 1u)) >> 16);  // RNE
}

__device__ __forceinline__ void gload_lds16(const unsigned short* g, unsigned short* l) {
  __builtin_amdgcn_global_load_lds(
      (__attribute__((address_space(1))) void*)g,
      (__attribute__((address_space(3))) void*)l,
      16, 0, 0);
}

// ---- elementwise fp32 -> bf16 convert (x) ----
__global__ void cvt_x_kernel(const float* __restrict__ in, unsigned short* __restrict__ out, int n4) {
  int idx = blockIdx.x * blockDim.x + threadIdx.x;
  int stride = gridDim.x * blockDim.x;
  const float4* in4 = (const float4*)in;
  ushort4* out4 = (ushort4*)out;
  for (int i = idx; i < n4; i += stride) {
    float4 f = in4[i];
    ushort4 o;
    o.x = f2bf(f.x); o.y = f2bf(f.y); o.z = f2bf(f.z); o.w = f2bf(f.w);
    out4[i] = o;
  }
}

// ---- tiled transpose + convert: in fp32 [R][C] per expert -> out bf16 [C][R] ----
__global__ void transpose_cvt_kernel(const float* __restrict__ in, unsigned short* __restrict__ out,
                                     int R, int C) {
  __shared__ float tile[32][33];
  const size_t eoff = (size_t)blockIdx.z * R * C;
  const float* src = in + eoff;
  unsigned short* dst = out + eoff;
  const int c0 = blockIdx.x * 32, r0 = blockIdx.y * 32;
  const int tx = threadIdx.x, ty = threadIdx.y;
#pragma unroll
  for (int i = 0; i < 4; ++i)
    tile[ty + 8 * i][tx] = src[(size_t)(r0 + ty + 8 * i) * C + c0 + tx];
  __syncthreads();
#pragma unroll
  for (int i = 0; i < 4; ++i)
    dst[(size_t)(c0 + ty + 8 * i) * R + r0 + tx] = f2bf(tile[tx][ty + 8 * i]);
}

// ---- 128x128-tile bf16 MFMA GEMM (m97 structure), B^T layout, lda=ldb=K ----
// A: [rows][K] bf16, Bt: [E][Ncols][K] bf16. Output row mapping is the x/h row space:
// global row = (b*E_+e)*N_ + local_n, with m enumerating (b, local_n) per expert.
template <int K, bool GELU>
__global__ __launch_bounds__(256)
void gemm128_kernel(const unsigned short* __restrict__ A,
                    const unsigned short* __restrict__ Bt,
                    const float* __restrict__ bias,
                    unsigned short* __restrict__ OutBf,
                    float* __restrict__ OutF,
                    int Ncols) {
  __shared__ __align__(16) unsigned short Alds[128 * 64];
  __shared__ __align__(16) unsigned short Blds[128 * 64];

  const int e = blockIdx.z;
  const int m0 = blockIdx.x * 128;
  const int n0 = blockIdx.y * 128;
  const int b = m0 >> 10;
  const int nl = m0 & 1023;
  const size_t arow0 = (size_t)((b * E_ + e) * N_ + nl);

  const unsigned short* Ab = A + arow0 * K;
  const unsigned short* Bb = Bt + (size_t)e * Ncols * K + (size_t)n0 * K;

  const int tid = threadIdx.x;
  const int wid = tid >> 6;
  const int lane = tid & 63;
  const int lr = lane >> 3;          // staging: row within 8-row chunk
  const int lc = (lane & 7) * 8;     // staging: col (8 bf16 = 16B)
  const int wr = wid >> 1, wc = wid & 1;

  const unsigned short* aSrc[4];
  const unsigned short* bSrc[4];
  unsigned short* aDst[4];
  unsigned short* bDst[4];
#pragma unroll
  for (int j = 0; j < 4; ++j) {
    const int c = wid * 4 + j;  // chunk 0..15, rows c*8..c*8+7
    aSrc[j] = Ab + (size_t)(c * 8 + lr) * K + lc;
    bSrc[j] = Bb + (size_t)(c * 8 + lr) * K + lc;
    aDst[j] = &Alds[c * 512];
    bDst[j] = &Blds[c * 512];
  }

  f32x4 acc[4][4];
#pragma unroll
  for (int mi = 0; mi < 4; ++mi)
#pragma unroll
    for (int ni = 0; ni < 4; ++ni)
      acc[mi][ni] = (f32x4){0.f, 0.f, 0.f, 0.f};

  const int fr = lane & 15;
  const int kgrp = (lane >> 4) * 8;

  for (int k0 = 0; k0 < K; k0 += 64) {
    __syncthreads();  // previous compute done before LDS overwrite
#pragma unroll
    for (int j = 0; j < 4; ++j) {
      gload_lds16(aSrc[j] + k0, aDst[j]);
      gload_lds16(bSrc[j] + k0, bDst[j]);
    }
    __syncthreads();  // vmcnt(0)-drain: staged tiles visible
#pragma unroll
    for (int kk = 0; kk < 64; kk += 32) {
      bf16x8 av[4], bv[4];
#pragma unroll
      for (int i = 0; i < 4; ++i) {
        av[i] = *(const bf16x8*)&Alds[(wr * 64 + i * 16 + fr) * 64 + kk + kgrp];
        bv[i] = *(const bf16x8*)&Blds[(wc * 64 + i * 16 + fr) * 64 + kk + kgrp];
      }
#pragma unroll
      for (int mi = 0; mi < 4; ++mi)
#pragma unroll
        for (int ni = 0; ni < 4; ++ni)
          acc[mi][ni] = __builtin_amdgcn_mfma_f32_16x16x32_bf16(av[mi], bv[ni], acc[mi][ni], 0, 0, 0);
    }
  }

  // epilogue: C/D layout col=lane&15, row=4*(lane>>4)+j  [m89-verified]
  const int rb = (lane >> 4) * 4;
#pragma unroll
  for (int ni = 0; ni < 4; ++ni) {
    const int gc = n0 + wc * 64 + ni * 16 + fr;
    const float bval = bias[(size_t)e * Ncols + gc];
#pragma unroll
    for (int mi = 0; mi < 4; ++mi) {
      const int rloc = wr * 64 + mi * 16 + rb;
#pragma unroll
      for (int j = 0; j < 4; ++j) {
        float v = acc[mi][ni][j] + bval;
        const size_t orow = arow0 + (size_t)(rloc + j);
        if (GELU) {
          float g = 0.5f * v * (1.0f + erff(v * 0.70710678118654752f));
          OutBf[orow * Ncols + gc] = f2bf(g);
        } else {
          OutF[orow * Ncols + gc] = v;
        }
      }
    }
  }
}

extern "C" void kernel_launch(void* const* d_in, const int* in_sizes, int n_in,
                              void* d_out, int out_size, void* d_ws, size_t ws_size,
                              hipStream_t stream) {
  const float* x  = (const float*)d_in[0];
  const float* w1 = (const float*)d_in[1];
  const float* b1 = (const float*)d_in[2];
  const float* w2 = (const float*)d_in[3];
  const float* b2 = (const float*)d_in[4];
  float* out = (float*)d_out;

  const size_t xN  = (size_t)B_ * E_ * N_ * D_;  // 16,777,216
  const size_t w1N = (size_t)E_ * D_ * H_;       // 33,554,432
  const size_t w2N = (size_t)E_ * H_ * D_;       // 33,554,432
  const size_t hN  = (size_t)B_ * E_ * N_ * H_;  // 67,108,864
  const size_t needed = (xN + w1N + w2N + hN) * 2;  // ~302 MB
  if (ws_size < needed) return;  // diagnostic: leaves output poisoned

  unsigned short* xb  = (unsigned short*)d_ws;
  unsigned short* w1t = xb + xN;   // [E][H][D] bf16
  unsigned short* w2t = w1t + w1N; // [E][D][H] bf16
  unsigned short* hb  = w2t + w2N; // [B][E][N][H] bf16

  cvt_x_kernel<<<2048, 256, 0, stream>>>(x, xb, (int)(xN / 4));
  dim3 tb(32, 8);
  // w1 [E][D][H] -> w1t [E][H][D]
  transpose_cvt_kernel<<<dim3(H_ / 32, D_ / 32, E_), tb, 0, stream>>>(w1, w1t, D_, H_);
  // w2 [E][H][D] -> w2t [E][D][H]
  transpose_cvt_kernel<<<dim3(D_ / 32, H_ / 32, E_), tb, 0, stream>>>(w2, w2t, H_, D_);

  // GEMM1: h = gelu(x @ w1 + b1), K=1024, Ncols=H
  gemm128_kernel<D_, true><<<dim3(16, H_ / 128, E_), 256, 0, stream>>>(xb, w1t, b1, hb, nullptr, H_);
  // GEMM2: out = h @ w2 + b2, K=4096, Ncols=D
  gemm128_kernel<H_, false><<<dim3(16, D_ / 128, E_), 256, 0, stream>>>(hb, w2t, b2, nullptr, out, D_);
}

// Round 2
// 463.929 us; speedup vs baseline: 1.3251x; 1.3251x over previous
//
#include <hip/hip_runtime.h>
#include <stdint.h>

#define B_ 2
#define E_ 8
#define N_ 1024
#define D_ 1024
#define H_ 4096

typedef float f32x4 __attribute__((ext_vector_type(4)));
typedef __bf16 bf16x8 __attribute__((ext_vector_type(8)));

__device__ __forceinline__ unsigned short f2bf(float f) {
  union { float f; uint32_t u; } v; v.f = f;
  uint32_t u = v.u;
  return (unsigned short)((u + 0x7FFFu + ((u >> 16) & 1u)) >> 16);  // RNE
}

__device__ __forceinline__ void gload_lds16(const unsigned short* g, unsigned short* l) {
  __builtin_amdgcn_global_load_lds(
      (__attribute__((address_space(1))) void*)g,
      (__attribute__((address_space(3))) void*)l,
      16, 0, 0);
}

// ---- elementwise fp32 -> bf16 convert (x) ----
__global__ void cvt_x_kernel(const float* __restrict__ in, unsigned short* __restrict__ out, int n4) {
  int idx = blockIdx.x * blockDim.x + threadIdx.x;
  int stride = gridDim.x * blockDim.x;
  const float4* in4 = (const float4*)in;
  ushort4* out4 = (ushort4*)out;
  for (int i = idx; i < n4; i += stride) {
    float4 f = in4[i];
    ushort4 o;
    o.x = f2bf(f.x); o.y = f2bf(f.y); o.z = f2bf(f.z); o.w = f2bf(f.w);
    out4[i] = o;
  }
}

// ---- tiled transpose + convert: in fp32 [R][C] per expert -> out bf16 [C][R] ----
__global__ void transpose_cvt_kernel(const float* __restrict__ in, unsigned short* __restrict__ out,
                                     int R, int C) {
  __shared__ float tile[32][33];
  const size_t eoff = (size_t)blockIdx.z * R * C;
  const float* src = in + eoff;
  unsigned short* dst = out + eoff;
  const int c0 = blockIdx.x * 32, r0 = blockIdx.y * 32;
  const int tx = threadIdx.x, ty = threadIdx.y;
#pragma unroll
  for (int i = 0; i < 4; ++i)
    tile[ty + 8 * i][tx] = src[(size_t)(r0 + ty + 8 * i) * C + c0 + tx];
  __syncthreads();
#pragma unroll
  for (int i = 0; i < 4; ++i)
    dst[(size_t)(c0 + ty + 8 * i) * R + r0 + tx] = f2bf(tile[tx][ty + 8 * i]);
}

// ============================================================================
// 256x256-tile, BK=64, 8-wave (2x4), 8-phase (4 per K-tile) bf16 MFMA GEMM.
// LDS: [buf][A,B][khalf][256 rows][32 k] bf16, 128 KiB total, dbuf.
// T2 st-swizzle: 16B slot s' = s ^ ((row>>1)&3), applied via pre-swizzled
// global source (linear gload_lds dest) + swizzled ds_read address.
// T4 counted vmcnt(4) at tile boundaries only; T5 setprio around MFMA.
// Stage rotation per compute(t): P1->t+1.Akh1, P2->t+1.Bkh1,
//                                P3->t+2.Akh0, P4->t+2.Bkh0.
// ============================================================================
template <int K, int NCOLS, bool GELU>
__global__ __launch_bounds__(512, 2)
void gemm256_kernel(const unsigned short* __restrict__ A,
                    const unsigned short* __restrict__ Bt,
                    const float* __restrict__ bias,
                    unsigned short* __restrict__ OutBf,
                    float* __restrict__ OutF) {
  constexpr int MT = 2048 / 256;   // M tiles per expert (B_*N_ rows)
  constexpr int NTl = NCOLS / 256; // N tiles
  constexpr int NT = K / 64;       // K tiles

  __shared__ __align__(16) unsigned short lds[2][2][2][256 * 32];

  // T1: bijective XCD swizzle (gridDim.x % 8 == 0 for both GEMMs)
  const int nwg = gridDim.x;
  const int flat = blockIdx.x;
  const int swz = (flat & 7) * (nwg >> 3) + (flat >> 3);
  const int e = swz / (MT * NTl);
  const int rem = swz - e * (MT * NTl);
  const int nt = rem / MT;
  const int mt = rem - nt * MT;

  const int m0 = mt * 256;
  const int n0 = nt * 256;
  const int b = m0 >> 10;
  const int nl = m0 & 1023;
  const size_t arow0 = (size_t)((b * E_ + e) * N_ + nl);

  const unsigned short* Ab = A + arow0 * K;
  const unsigned short* Bb = Bt + ((size_t)e * NCOLS + n0) * K;

  const int tid = threadIdx.x;
  const int w = tid >> 6;
  const int lane = tid & 63;
  const int wr = w >> 2;        // 0..1  (M half: 128 rows)
  const int wc = w & 3;         // 0..3  (N quarter: 64 cols)
  const int fr = lane & 15;
  const int kg = lane >> 4;     // 0..3 (16B k-slot)
  const int sxor = kg ^ ((lane >> 1) & 3);  // swizzled read slot

  // staging source addressing (pre-swizzled so linear LDS dest ends up swizzled)
  const int scol = (((lane & 3) ^ ((lane >> 3) & 3)) << 3);  // k element offset
  const int srow0 = (w * 2 + 0) * 16 + (lane >> 2);
  const int srow1 = (w * 2 + 1) * 16 + (lane >> 2);
  const unsigned short* aS0 = Ab + (size_t)srow0 * K + scol;
  const unsigned short* aS1 = Ab + (size_t)srow1 * K + scol;
  const unsigned short* bS0 = Bb + (size_t)srow0 * K + scol;
  const unsigned short* bS1 = Bb + (size_t)srow1 * K + scol;

  // per-thread LDS read bases (element units within one [256*32] slot)
  const int aBase = (wr * 128 + fr) * 32 + sxor * 8;
  const int bBase = (wc * 64 + fr) * 32 + sxor * 8;

#define STAGE_A(buf, kh, t) do {                                   \
    unsigned short* d_ = &lds[(buf)][0][(kh)][w * 1024];           \
    const size_t ko_ = (size_t)(t) * 64 + (kh) * 32;               \
    gload_lds16(aS0 + ko_, d_);                                    \
    gload_lds16(aS1 + ko_, d_ + 512);                              \
  } while (0)
#define STAGE_B(buf, kh, t) do {                                   \
    unsigned short* d_ = &lds[(buf)][1][(kh)][w * 1024];           \
    const size_t ko_ = (size_t)(t) * 64 + (kh) * 32;               \
    gload_lds16(bS0 + ko_, d_);                                    \
    gload_lds16(bS1 + ko_, d_ + 512);                              \
  } while (0)

  f32x4 acc[8][4];
#pragma unroll
  for (int i = 0; i < 8; ++i)
#pragma unroll
    for (int j = 0; j < 4; ++j)
      acc[i][j] = (f32x4){0.f, 0.f, 0.f, 0.f};

  // prologue: tile0 fully + tile1 khalf0; leave tile1's 2 half-tiles in flight
  STAGE_A(0, 0, 0); STAGE_B(0, 0, 0);
  STAGE_A(0, 1, 0); STAGE_B(0, 1, 0);
  STAGE_A(1, 0, 1); STAGE_B(1, 0, 1);
  asm volatile("s_waitcnt vmcnt(4)" ::: "memory");
  __builtin_amdgcn_s_barrier();

  for (int t = 0; t < NT; ++t) {
    const int c = t & 1;
    bf16x8 av[4], bv[4];

    // ---- P1: kh=0, rows rh=0 ----
#pragma unroll
    for (int i = 0; i < 4; ++i) {
      av[i] = *(const bf16x8*)&lds[c][0][0][aBase + i * 16 * 32];
      bv[i] = *(const bf16x8*)&lds[c][1][0][bBase + i * 16 * 32];
    }
    if (t + 1 < NT) STAGE_A(c ^ 1, 1, t + 1);
    __builtin_amdgcn_s_barrier();
    __builtin_amdgcn_s_setprio(1);
#pragma unroll
    for (int mi = 0; mi < 4; ++mi)
#pragma unroll
      for (int ni = 0; ni < 4; ++ni)
        acc[mi][ni] = __builtin_amdgcn_mfma_f32_16x16x32_bf16(av[mi], bv[ni], acc[mi][ni], 0, 0, 0);
    __builtin_amdgcn_s_setprio(0);
    __builtin_amdgcn_s_barrier();

    // ---- P2: kh=0, rows rh=1 (reuse bv) ----
#pragma unroll
    for (int i = 0; i < 4; ++i)
      av[i] = *(const bf16x8*)&lds[c][0][0][aBase + (64 + i * 16) * 32];
    if (t + 1 < NT) STAGE_B(c ^ 1, 1, t + 1);
    __builtin_amdgcn_s_barrier();
    __builtin_amdgcn_s_setprio(1);
#pragma unroll
    for (int mi = 0; mi < 4; ++mi)
#pragma unroll
      for (int ni = 0; ni < 4; ++ni)
        acc[4 + mi][ni] = __builtin_amdgcn_mfma_f32_16x16x32_bf16(av[mi], bv[ni], acc[4 + mi][ni], 0, 0, 0);
    __builtin_amdgcn_s_setprio(0);
    __builtin_amdgcn_s_barrier();

    // ---- P3: kh=1, rows rh=0 ----
#pragma unroll
    for (int i = 0; i < 4; ++i) {
      av[i] = *(const bf16x8*)&lds[c][0][1][aBase + i * 16 * 32];
      bv[i] = *(const bf16x8*)&lds[c][1][1][bBase + i * 16 * 32];
    }
    if (t + 2 < NT) STAGE_A(c, 0, t + 2);
    __builtin_amdgcn_s_barrier();
    __builtin_amdgcn_s_setprio(1);
#pragma unroll
    for (int mi = 0; mi < 4; ++mi)
#pragma unroll
      for (int ni = 0; ni < 4; ++ni)
        acc[mi][ni] = __builtin_amdgcn_mfma_f32_16x16x32_bf16(av[mi], bv[ni], acc[mi][ni], 0, 0, 0);
    __builtin_amdgcn_s_setprio(0);
    __builtin_amdgcn_s_barrier();

    // ---- P4: kh=1, rows rh=1 (reuse bv) ----
#pragma unroll
    for (int i = 0; i < 4; ++i)
      av[i] = *(const bf16x8*)&lds[c][0][1][aBase + (64 + i * 16) * 32];
    if (t + 2 < NT) STAGE_B(c, 0, t + 2);
    __builtin_amdgcn_s_barrier();
    __builtin_amdgcn_s_setprio(1);
#pragma unroll
    for (int mi = 0; mi < 4; ++mi)
#pragma unroll
      for (int ni = 0; ni < 4; ++ni)
        acc[4 + mi][ni] = __builtin_amdgcn_mfma_f32_16x16x32_bf16(av[mi], bv[ni], acc[4 + mi][ni], 0, 0, 0);
    __builtin_amdgcn_s_setprio(0);
    // tile boundary: all of tile t+1 must be visible; 2 half-tiles stay in flight
    asm volatile("s_waitcnt vmcnt(4)" ::: "memory");
    __builtin_amdgcn_s_barrier();
  }

#undef STAGE_A
#undef STAGE_B

  // epilogue: C/D layout col=lane&15, row=(lane>>4)*4+j  [round-1 verified]
  const int rb = kg * 4;
#pragma unroll
  for (int ni = 0; ni < 4; ++ni) {
    const int gc = n0 + wc * 64 + ni * 16 + fr;
    const float bval = bias[(size_t)e * NCOLS + gc];
#pragma unroll
    for (int MI = 0; MI < 8; ++MI) {
      const size_t orow = arow0 + (size_t)(wr * 128 + MI * 16 + rb);
#pragma unroll
      for (int j = 0; j < 4; ++j) {
        float v = acc[MI][ni][j] + bval;
        if constexpr (GELU) {
          float g = 0.5f * v * (1.0f + erff(v * 0.70710678118654752f));
          OutBf[(orow + j) * NCOLS + gc] = f2bf(g);
        } else {
          OutF[(orow + j) * NCOLS + gc] = v;
        }
      }
    }
  }
}

extern "C" void kernel_launch(void* const* d_in, const int* in_sizes, int n_in,
                              void* d_out, int out_size, void* d_ws, size_t ws_size,
                              hipStream_t stream) {
  const float* x  = (const float*)d_in[0];
  const float* w1 = (const float*)d_in[1];
  const float* b1 = (const float*)d_in[2];
  const float* w2 = (const float*)d_in[3];
  const float* b2 = (const float*)d_in[4];
  float* out = (float*)d_out;

  const size_t xN  = (size_t)B_ * E_ * N_ * D_;
  const size_t w1N = (size_t)E_ * D_ * H_;
  const size_t w2N = (size_t)E_ * H_ * D_;
  const size_t hN  = (size_t)B_ * E_ * N_ * H_;
  const size_t needed = (xN + w1N + w2N + hN) * 2;
  if (ws_size < needed) return;

  unsigned short* xb  = (unsigned short*)d_ws;
  unsigned short* w1t = xb + xN;   // [E][H][D] bf16
  unsigned short* w2t = w1t + w1N; // [E][D][H] bf16
  unsigned short* hb  = w2t + w2N; // [B][E][N][H] bf16

  cvt_x_kernel<<<2048, 256, 0, stream>>>(x, xb, (int)(xN / 4));
  dim3 tb(32, 8);
  transpose_cvt_kernel<<<dim3(H_ / 32, D_ / 32, E_), tb, 0, stream>>>(w1, w1t, D_, H_);
  transpose_cvt_kernel<<<dim3(D_ / 32, H_ / 32, E_), tb, 0, stream>>>(w2, w2t, H_, D_);

  // GEMM1: h = gelu(x @ w1 + b1); M-tiles 8, N-tiles 16, E 8 -> 1024 blocks
  gemm256_kernel<D_, H_, true><<<8 * (H_ / 256) * E_, 512, 0, stream>>>(xb, w1t, b1, hb, nullptr);
  // GEMM2: out = h @ w2 + b2; 8 * 4 * 8 = 256 blocks
  gemm256_kernel<H_, D_, false><<<8 * (D_ / 256) * E_, 512, 0, stream>>>(hb, w2t, b2, nullptr, out);
}